// Round 1
// 206.007 us; speedup vs baseline: 1.0244x; 1.0244x over previous
//
#include <hip/hip_runtime.h>
#include <stdint.h>

typedef unsigned long long u64;
typedef unsigned int u32;
typedef float vf2 __attribute__((ext_vector_type(2)));

constexpr int Ccand = 32;   // candidates per row
constexpr int Evoc  = 512;  // vocab size
constexpr int Tgt   = 64;   // target_size

// ---- xor-partner exchange -------------------------------------------------
// j=1,2  : DPP quad_perm  (pure VALU, no LDS, no address math)
// j=4..16: ds_swizzle with immediate xor pattern (no address VALU)
// j=32   : bpermute-based __shfl_xor (crosses the 32-lane swizzle boundary)
template<int J>
__device__ __forceinline__ int shx32(int x) {
    if constexpr (J == 1)       return __builtin_amdgcn_update_dpp(0, x, 0xB1, 0xF, 0xF, true); // quad_perm [1,0,3,2]
    else if constexpr (J == 2)  return __builtin_amdgcn_update_dpp(0, x, 0x4E, 0xF, 0xF, true); // quad_perm [2,3,0,1]
    else if constexpr (J <= 16) return __builtin_amdgcn_ds_swizzle(x, (J << 10) | 0x1F);        // BitMode xor
    else                        return __shfl_xor(x, J);
}

// bitonic compare-exchange step; direction masks (lane&K2)==0 / (lane&J)==0 are
// 6 distinct values total -> CSE'd into SGPR masks, step is cmp + s_xnor + cndmask
template<int K2, int J>
__device__ __forceinline__ void cas_f32(float& a, int lane) {
    float o = __int_as_float(shx32<J>(__float_as_int(a)));
    bool keepMax = (((lane & K2) == 0) == ((lane & J) == 0));
    bool g = a > o;
    a = (keepMax == g) ? a : o;
}

template<int K2, int J>
__device__ __forceinline__ void cas_u64(u64& a, int lane) {
    int lo = shx32<J>((int)(u32)a);
    int hi = shx32<J>((int)(u32)(a >> 32));
    u64 o = ((u64)(u32)hi << 32) | (u32)lo;
    bool keepMax = (((lane & K2) == 0) == ((lane & J) == 0));
    bool g = a > o;
    a = (keepMax == g) ? a : o;
}

__device__ __forceinline__ void sort64_desc_f32(float& a, int lane) {
    cas_f32<2,1>(a,lane);
    cas_f32<4,2>(a,lane);   cas_f32<4,1>(a,lane);
    cas_f32<8,4>(a,lane);   cas_f32<8,2>(a,lane);   cas_f32<8,1>(a,lane);
    cas_f32<16,8>(a,lane);  cas_f32<16,4>(a,lane);  cas_f32<16,2>(a,lane);  cas_f32<16,1>(a,lane);
    cas_f32<32,16>(a,lane); cas_f32<32,8>(a,lane);  cas_f32<32,4>(a,lane);  cas_f32<32,2>(a,lane);  cas_f32<32,1>(a,lane);
    cas_f32<64,32>(a,lane); cas_f32<64,16>(a,lane); cas_f32<64,8>(a,lane);  cas_f32<64,4>(a,lane);  cas_f32<64,2>(a,lane); cas_f32<64,1>(a,lane);
}

__device__ __forceinline__ void sort64_desc_u64(u64& a, int lane) {
    cas_u64<2,1>(a,lane);
    cas_u64<4,2>(a,lane);   cas_u64<4,1>(a,lane);
    cas_u64<8,4>(a,lane);   cas_u64<8,2>(a,lane);   cas_u64<8,1>(a,lane);
    cas_u64<16,8>(a,lane);  cas_u64<16,4>(a,lane);  cas_u64<16,2>(a,lane);  cas_u64<16,1>(a,lane);
    cas_u64<32,16>(a,lane); cas_u64<32,8>(a,lane);  cas_u64<32,4>(a,lane);  cas_u64<32,2>(a,lane);  cas_u64<32,1>(a,lane);
    cas_u64<64,32>(a,lane); cas_u64<64,16>(a,lane); cas_u64<64,8>(a,lane);  cas_u64<64,4>(a,lane);  cas_u64<64,2>(a,lane); cas_u64<64,1>(a,lane);
}

// One wave (64 lanes) per row. Lane l owns cols {4l..4l+3} and {256+4l..+3}.
__global__ __launch_bounds__(256, 8) void cooc_expand(
    const int* __restrict__ cand_ids,
    const float* __restrict__ cand_scores,
    const float* __restrict__ cooc,
    float* __restrict__ out_ids,
    float* __restrict__ out_scores,
    int B)
{
    const int lane = threadIdx.x & 63;
    const int wid  = threadIdx.x >> 6;
    const int row  = blockIdx.x * 4 + wid;
    __shared__ u64 buf[4][64];     // per-wave 64-slot window (2 KB/block)
    __shared__ u32 maskw[4][16];   // per-wave 512-bit candidate bitmap
    if (row >= B) return;   // never taken (B % 4 == 0); no block barriers used

    // ---- load candidates (lanes 0..31); start the LDS candidate bitmap early ----
    if (lane < 16) maskw[wid][lane] = 0u;
    int   my_id = -1;
    float my_s  = 0.0f;
    if (lane < Ccand) {
        my_id = cand_ids[(size_t)row * Ccand + lane];
        my_s  = cand_scores[(size_t)row * Ccand + lane];
    }
    __threadfence_block();  // zero before or (same-wave LDS ordering)
    if (lane < Ccand)
        atomicOr(&maskw[wid][(u32)my_id >> 5], 1u << (my_id & 31));  // idempotent, dups fine

    // ---- fused duplicate-merge + rank, np.add.at order (ascending j, from 0.0) ----
    u32 eqm = 0, ltm = 0;
    float sm = 0.0f;
    #pragma unroll
    for (int j = 0; j < Ccand; ++j) {
        int   idj = __builtin_amdgcn_readlane(my_id, j);
        float sj  = __int_as_float(__builtin_amdgcn_readlane(__float_as_int(my_s), j));
        bool eq = (idj == my_id);
        eqm |= eq ? (1u << j) : 0u;
        ltm |= (idj < my_id) ? (1u << j) : 0u;
        sm  += eq ? sj : 0.0f;   // serial ascending-j add: matches np.add.at exactly
    }
    u32 below = (1u << (lane & 31)) - 1u;
    bool alive = (lane < Ccand) && ((eqm & below) == 0u);  // first occurrence of my_id
    u64 aball = __ballot(alive);
    int m  = __popcll(aball);                 // distinct ids (wave-uniform, >=1)
    int rk = __popc(ltm & (u32)aball);        // rank among distinct ids, ascending id

    int dst = alive ? rk : ((lane < 32) ? (lane + 32) : lane);
    int sorted_id = __builtin_amdgcn_ds_permute(dst << 2, my_id);
    int sorted_sb = __builtin_amdgcn_ds_permute(dst << 2, __float_as_int(sm));

    // ---- accumulation: ceil(m/4) iters x 4 ids; readlane -> SGPR base addr;
    // packed v_pk_fma_f32 (bit-exact per component); t>=m: s=0,
    // fma(0,·,acc)==acc bit-exact (acc stays >= +0). Loop clamped to m so dup
    // rows skip loads entirely and no garbage rows pollute L1.
    vf2 acc2[4];
    acc2[0] = (vf2){0.f, 0.f}; acc2[1] = (vf2){0.f, 0.f};
    acc2[2] = (vf2){0.f, 0.f}; acc2[3] = (vf2){0.f, 0.f};
    const int l4 = lane << 2;
    #pragma unroll 1
    for (int t = 0; t < m; t += 4) {
        int   e[4];
        float s[4];
        #pragma unroll
        for (int u = 0; u < 4; ++u) {
            int idx  = t + u;
            int idxc = (idx < m) ? idx : (m - 1);   // clamp -> valid (L1-hot) row
            e[u] = __builtin_amdgcn_readlane(sorted_id, idxc) & 511;
            s[u] = (idx < m) ? __int_as_float(__builtin_amdgcn_readlane(sorted_sb, idx)) : 0.0f;
        }
        float4 A[4], Bv[4];
        #pragma unroll
        for (int u = 0; u < 4; ++u) {
            const float* rp = cooc + ((size_t)e[u] << 9);
            A[u]  = *reinterpret_cast<const float4*>(rp + l4);
            Bv[u] = *reinterpret_cast<const float4*>(rp + 256 + l4);
        }
        #pragma unroll
        for (int u = 0; u < 4; ++u) {
            vf2 sv2; sv2[0] = s[u]; sv2[1] = s[u];
            vf2 a0; a0[0] = A[u].x;  a0[1] = A[u].y;
            vf2 a1; a1[0] = A[u].z;  a1[1] = A[u].w;
            vf2 b0; b0[0] = Bv[u].x; b0[1] = Bv[u].y;
            vf2 b1; b1[0] = Bv[u].z; b1[1] = Bv[u].w;
            acc2[0] = __builtin_elementwise_fma(sv2, a0, acc2[0]);
            acc2[1] = __builtin_elementwise_fma(sv2, a1, acc2[1]);
            acc2[2] = __builtin_elementwise_fma(sv2, b0, acc2[2]);
            acc2[3] = __builtin_elementwise_fma(sv2, b1, acc2[3]);
        }
    }

    // ---- masked-slot bits from the LDS bitmap (reference: cooc_scores[b,e] = -inf).
    // col c=4l+q -> word l>>3 bit 4(l&7)+q ; col 256+4l+q -> word 8+(l>>3) same bit.
    __threadfence_block();
    u32 wA = maskw[wid][lane >> 3];
    u32 wB = maskw[wid][8 + (lane >> 3)];
    int sh = (lane & 7) << 2;
    u32 mb = ((wA >> sh) & 15u) | (((wB >> sh) & 15u) << 4);

    // ---- original-layout values; masked -> -1.0 (strictly below all) ----
    float v[8];
    v[0] = acc2[0][0]; v[1] = acc2[0][1]; v[2] = acc2[1][0]; v[3] = acc2[1][1];
    v[4] = acc2[2][0]; v[5] = acc2[2][1]; v[6] = acc2[3][0]; v[7] = acc2[3][1];
    #pragma unroll
    for (int j = 0; j < 8; ++j)
        if ((mb >> j) & 1u) v[j] = -1.0f;

    // ---- L32: 32nd largest of per-lane maxima; T >= L32 and every
    // top-32 element (incl. ==T ties) has v >= L32; also S_tot >= 32 ----
    float mx8 = v[0];
    #pragma unroll
    for (int j = 1; j < 8; ++j) mx8 = fmaxf(mx8, v[j]);
    float srt = mx8;
    sort64_desc_f32(srt, lane);
    float L32 = __int_as_float(__builtin_amdgcn_readlane(__float_as_int(srt), 31));

    // ---- survivor count + exclusive prefix via ballot/mbcnt (no shfl_up chain) ----
    int cnt = 0;
    #pragma unroll
    for (int j = 0; j < 8; ++j) cnt += (v[j] >= L32) ? 1 : 0;
    int sbase = 0, S_tot = 0;
    #pragma unroll
    for (int b = 0; b < 4; ++b) {
        u64 bal = __ballot(((cnt >> b) & 1) != 0);
        int pc = __builtin_amdgcn_mbcnt_hi((u32)(bal >> 32),
                 __builtin_amdgcn_mbcnt_lo((u32)bal, 0));
        sbase += pc << b;
        S_tot += ((int)__popcll(bal)) << b;
    }

    // ---- chunked scatter + sort + merge-prune over 64-slot windows.
    // Chunk 0 is the whole story for ~99.98% of rows (S_tot <= 64).
    // Keys (valbits<<32 | 511-col) unique; desc u64 order == np stable
    // top-k order (value desc, col asc). ----
    int nchunk = (S_tot + 63) >> 6;   // wave-uniform >= 1
    u64 cur = 0ull;
    #pragma unroll 1
    for (int c = 0; c < nchunk; ++c) {
        const int lo = c << 6;
        // scatter survivors whose slot falls in [lo, lo+64)
        int slot = sbase;
        #pragma unroll
        for (int j = 0; j < 8; ++j) {
            bool s = (v[j] >= L32);
            int  rel = slot - lo;
            if (s && rel >= 0 && rel < 64) {
                int col = (j < 4) ? (l4 + j) : (256 + l4 + (j - 4));
                buf[wid][rel] = ((u64)__float_as_uint(v[j]) << 32) | (u32)(511 - col);
            }
            slot += s ? 1 : 0;
        }
        __threadfence_block();
        u64 nxt = (lo + lane < S_tot) ? buf[wid][lane] : 0ull;
        __threadfence_block();   // reads complete before next chunk's writes
        sort64_desc_u64(nxt, lane);
        if (c == 0) {
            cur = nxt;
        } else {
            u64 o = __shfl_xor(nxt, 63);           // nxt[63-lane]
            cur = (cur >= o) ? cur : o;            // top-64 of 128, bitonic
            cas_u64<64,32>(cur, lane);             // descending cleanup
            cas_u64<64,16>(cur, lane);
            cas_u64<64,8>(cur, lane);
            cas_u64<64,4>(cur, lane);
            cas_u64<64,2>(cur, lane);
            cas_u64<64,1>(cur, lane);
        }
    }
    // lane r now holds rank-r key (r < 32 are the selected top-32)

    // ---- coalesced stores: [orig 32 | selected 32] ----
    int src = (lane >= 32) ? (lane - 32) : 0;
    u64 kk = __shfl(cur, src);
    const size_t ob = (size_t)row * Tgt;
    float oid, osc;
    if (lane < Ccand) {
        oid = (float)my_id;
        osc = my_s;
    } else {
        oid = (float)(int)(511 - (u32)(kk & 511ull));
        osc = __uint_as_float((u32)(kk >> 32));
    }
    out_ids[ob + lane]    = oid;
    out_scores[ob + lane] = osc;
}

extern "C" void kernel_launch(void* const* d_in, const int* in_sizes, int n_in,
                              void* d_out, int out_size, void* d_ws, size_t ws_size,
                              hipStream_t stream) {
    const int*   ids    = (const int*)d_in[0];
    const float* scores = (const float*)d_in[1];
    const float* cooc   = (const float*)d_in[2];
    int B = in_sizes[0] / Ccand;
    float* out_ids    = (float*)d_out;
    float* out_scores = out_ids + (size_t)B * Tgt;
    int blocks = (B + 3) / 4;
    hipLaunchKernelGGL(cooc_expand, dim3(blocks), dim3(256), 0, stream,
                       ids, scores, cooc, out_ids, out_scores, B);
}

// Round 2
// 203.667 us; speedup vs baseline: 1.0362x; 1.0115x over previous
//
#include <hip/hip_runtime.h>
#include <stdint.h>

typedef unsigned long long u64;
typedef unsigned int u32;
typedef float vf2 __attribute__((ext_vector_type(2)));

constexpr int Ccand = 32;   // candidates per row
constexpr int Evoc  = 512;  // vocab size
constexpr int Tgt   = 64;   // target_size

// ---- xor-partner exchange -------------------------------------------------
// j=1,2  : DPP quad_perm  (pure VALU, no LDS, no address math)
// j=4..16: ds_swizzle with immediate xor pattern (no address VALU)
// j=32   : bpermute-based __shfl_xor (crosses the 32-lane swizzle boundary)
template<int J>
__device__ __forceinline__ int shx32(int x) {
    if constexpr (J == 1)       return __builtin_amdgcn_update_dpp(0, x, 0xB1, 0xF, 0xF, true); // quad_perm [1,0,3,2]
    else if constexpr (J == 2)  return __builtin_amdgcn_update_dpp(0, x, 0x4E, 0xF, 0xF, true); // quad_perm [2,3,0,1]
    else if constexpr (J <= 16) return __builtin_amdgcn_ds_swizzle(x, (J << 10) | 0x1F);        // BitMode xor
    else                        return __shfl_xor(x, J);
}

// bitonic compare-exchange step; direction masks (lane&K2)==0 / (lane&J)==0 are
// 6 distinct values total -> CSE'd into SGPR masks, step is cmp + s_xnor + cndmask
template<int K2, int J>
__device__ __forceinline__ void cas_f32(float& a, int lane) {
    float o = __int_as_float(shx32<J>(__float_as_int(a)));
    bool keepMax = (((lane & K2) == 0) == ((lane & J) == 0));
    bool g = a > o;
    a = (keepMax == g) ? a : o;
}

template<int K2, int J>
__device__ __forceinline__ void cas_u64(u64& a, int lane) {
    int lo = shx32<J>((int)(u32)a);
    int hi = shx32<J>((int)(u32)(a >> 32));
    u64 o = ((u64)(u32)hi << 32) | (u32)lo;
    bool keepMax = (((lane & K2) == 0) == ((lane & J) == 0));
    bool g = a > o;
    a = (keepMax == g) ? a : o;
}

__device__ __forceinline__ void sort64_desc_f32(float& a, int lane) {
    cas_f32<2,1>(a,lane);
    cas_f32<4,2>(a,lane);   cas_f32<4,1>(a,lane);
    cas_f32<8,4>(a,lane);   cas_f32<8,2>(a,lane);   cas_f32<8,1>(a,lane);
    cas_f32<16,8>(a,lane);  cas_f32<16,4>(a,lane);  cas_f32<16,2>(a,lane);  cas_f32<16,1>(a,lane);
    cas_f32<32,16>(a,lane); cas_f32<32,8>(a,lane);  cas_f32<32,4>(a,lane);  cas_f32<32,2>(a,lane);  cas_f32<32,1>(a,lane);
    cas_f32<64,32>(a,lane); cas_f32<64,16>(a,lane); cas_f32<64,8>(a,lane);  cas_f32<64,4>(a,lane);  cas_f32<64,2>(a,lane); cas_f32<64,1>(a,lane);
}

__device__ __forceinline__ void sort64_desc_u64(u64& a, int lane) {
    cas_u64<2,1>(a,lane);
    cas_u64<4,2>(a,lane);   cas_u64<4,1>(a,lane);
    cas_u64<8,4>(a,lane);   cas_u64<8,2>(a,lane);   cas_u64<8,1>(a,lane);
    cas_u64<16,8>(a,lane);  cas_u64<16,4>(a,lane);  cas_u64<16,2>(a,lane);  cas_u64<16,1>(a,lane);
    cas_u64<32,16>(a,lane); cas_u64<32,8>(a,lane);  cas_u64<32,4>(a,lane);  cas_u64<32,2>(a,lane);  cas_u64<32,1>(a,lane);
    cas_u64<64,32>(a,lane); cas_u64<64,16>(a,lane); cas_u64<64,8>(a,lane);  cas_u64<64,4>(a,lane);  cas_u64<64,2>(a,lane); cas_u64<64,1>(a,lane);
}

// reverse low 16 bits: bit t of result = bit (15-t) of x
__device__ __forceinline__ u32 rev16(u32 x) {
    return __builtin_bitreverse32(x) >> 16;
}

// One wave (64 lanes) per row. Lane l owns cols {4l..4l+3} and {256+4l..+3}.
__global__ __launch_bounds__(256, 8) void cooc_expand(
    const int* __restrict__ cand_ids,
    const float* __restrict__ cand_scores,
    const float* __restrict__ cooc,
    float* __restrict__ out_ids,
    float* __restrict__ out_scores,
    int B)
{
    const int lane = threadIdx.x & 63;
    const int wid  = threadIdx.x >> 6;
    const int row  = blockIdx.x * 4 + wid;
    __shared__ u64 buf[4][64];     // per-wave 64-slot window (2 KB/block)
    __shared__ u32 maskw[4][16];   // per-wave 512-bit candidate bitmap
    if (row >= B) return;   // never taken (B % 4 == 0); no block barriers used

    // ---- load candidates (lanes 0..31); start the LDS candidate bitmap early ----
    if (lane < 16) maskw[wid][lane] = 0u;
    int   my_id = -1;
    float my_s  = 0.0f;
    if (lane < Ccand) {
        my_id = cand_ids[(size_t)row * Ccand + lane];
        my_s  = cand_scores[(size_t)row * Ccand + lane];
    }
    __threadfence_block();  // zero before or (same-wave LDS ordering)
    if (lane < Ccand)
        atomicOr(&maskw[wid][(u32)my_id >> 5], 1u << (my_id & 31));  // idempotent, dups fine

    // ---- all-pairs id compare, SPLIT across wave halves ------------------
    // lane l<32 compares id_l against j=0..15; lane l+32 compares the SAME
    // id (one shfl_xor) against j=16..31. 16 bpermute broadcasts (DS pipe)
    // instead of 32 readlanes (VALU pipe); one shfl_xor recombines masks.
    int pid = __shfl_xor(my_id, 32);              // lanes>=32: id of lane-32
    int qid = (lane < 32) ? my_id : pid;          // id this lane is responsible for
    const int jb4 = (lane < 32) ? 0 : (16 << 2);  // byte addr base of j-range
    u32 acc_eq = 0u, acc_lt = 0u;
    #pragma unroll
    for (int t = 0; t < 16; ++t) {
        int idj = __builtin_amdgcn_ds_bpermute(jb4 + (t << 2), my_id); // id_{jb+t}
        acc_eq = (acc_eq << 1) | (idj == qid ? 1u : 0u);
        acc_lt = (acc_lt << 1) | (idj <  qid ? 1u : 0u);
    }
    // bit t of rev16(acc) corresponds to j = jb + t
    u32 pk = (rev16(acc_eq) << 16) | rev16(acc_lt);
    u32 op = (u32)__shfl_xor((int)pk, 32);        // partner's masks (j=16..31 half)
    // full 32-bit masks over j=0..31 (valid for lanes<32; unused elsewhere)
    u32 eqm = (pk >> 16) | (op & 0xFFFF0000u);
    u32 ltm = (pk & 0xFFFFu) | (op << 16);

    u32 below = (1u << (lane & 31)) - 1u;
    bool alive = (lane < Ccand) && ((eqm & below) == 0u);  // first occurrence of my_id
    u64 aball = __ballot(alive);
    int m  = __popcll(aball);                 // distinct ids (wave-uniform, >=1)
    int rk = __popc(ltm & (u32)aball);        // rank among distinct ids, ascending id

    // ---- exact duplicate-merge (np.add.at ascending-j order) -------------
    // alive lane's own j is the LOWEST set bit of eqm; start from my_s and
    // add later matches ascending via ffs/bpermute. 0 iterations for ~38%
    // of rows, <=2 for nearly all others.
    float smv = my_s;
    u32 rem = alive ? (eqm & ~(1u << (lane & 31))) : 0u;
    while (__any(rem != 0u)) {
        int j = __ffs(rem) - 1;                // lowest set bit (ascending j)
        float sj = __int_as_float(__builtin_amdgcn_ds_bpermute(j << 2, __float_as_int(my_s)));
        smv += (rem != 0u) ? sj : 0.0f;        // +0.0 exact no-op (smv >= +0)
        rem &= rem - 1u;
    }

    int dst = alive ? rk : ((lane < 32) ? (lane + 32) : lane);
    int sorted_id = __builtin_amdgcn_ds_permute(dst << 2, my_id);
    int sorted_sb = __builtin_amdgcn_ds_permute(dst << 2, __float_as_int(smv));

    // ---- accumulation: ceil(m/4) iters x 4 ids; readlane -> SGPR base addr;
    // packed v_pk_fma_f32 (bit-exact per component); t>=m: s=0,
    // fma(0,·,acc)==acc bit-exact (acc stays >= +0). Loop clamped to m so dup
    // rows skip loads entirely and no garbage rows pollute L1.
    vf2 acc2[4];
    acc2[0] = (vf2){0.f, 0.f}; acc2[1] = (vf2){0.f, 0.f};
    acc2[2] = (vf2){0.f, 0.f}; acc2[3] = (vf2){0.f, 0.f};
    const int l4 = lane << 2;
    #pragma unroll 1
    for (int t = 0; t < m; t += 4) {
        int   e[4];
        float s[4];
        #pragma unroll
        for (int u = 0; u < 4; ++u) {
            int idx  = t + u;
            int idxc = (idx < m) ? idx : (m - 1);   // clamp -> valid (L1-hot) row
            e[u] = __builtin_amdgcn_readlane(sorted_id, idxc) & 511;
            s[u] = (idx < m) ? __int_as_float(__builtin_amdgcn_readlane(sorted_sb, idx)) : 0.0f;
        }
        float4 A[4], Bv[4];
        #pragma unroll
        for (int u = 0; u < 4; ++u) {
            const float* rp = cooc + ((size_t)e[u] << 9);
            A[u]  = *reinterpret_cast<const float4*>(rp + l4);
            Bv[u] = *reinterpret_cast<const float4*>(rp + 256 + l4);
        }
        #pragma unroll
        for (int u = 0; u < 4; ++u) {
            vf2 sv2; sv2[0] = s[u]; sv2[1] = s[u];
            vf2 a0; a0[0] = A[u].x;  a0[1] = A[u].y;
            vf2 a1; a1[0] = A[u].z;  a1[1] = A[u].w;
            vf2 b0; b0[0] = Bv[u].x; b0[1] = Bv[u].y;
            vf2 b1; b1[0] = Bv[u].z; b1[1] = Bv[u].w;
            acc2[0] = __builtin_elementwise_fma(sv2, a0, acc2[0]);
            acc2[1] = __builtin_elementwise_fma(sv2, a1, acc2[1]);
            acc2[2] = __builtin_elementwise_fma(sv2, b0, acc2[2]);
            acc2[3] = __builtin_elementwise_fma(sv2, b1, acc2[3]);
        }
    }

    // ---- masked-slot bits from the LDS bitmap (reference: cooc_scores[b,e] = -inf).
    // col c=4l+q -> word l>>3 bit 4(l&7)+q ; col 256+4l+q -> word 8+(l>>3) same bit.
    __threadfence_block();
    u32 wA = maskw[wid][lane >> 3];
    u32 wB = maskw[wid][8 + (lane >> 3)];
    int sh = (lane & 7) << 2;
    u32 mb = ((wA >> sh) & 15u) | (((wB >> sh) & 15u) << 4);

    // ---- original-layout values; masked -> -1.0 (strictly below all) ----
    float v[8];
    v[0] = acc2[0][0]; v[1] = acc2[0][1]; v[2] = acc2[1][0]; v[3] = acc2[1][1];
    v[4] = acc2[2][0]; v[5] = acc2[2][1]; v[6] = acc2[3][0]; v[7] = acc2[3][1];
    #pragma unroll
    for (int j = 0; j < 8; ++j)
        if ((mb >> j) & 1u) v[j] = -1.0f;

    // ---- L32: 32nd largest of per-lane maxima; L32 <= V32 (true 32nd of
    // all 512) and >=32 elements are >= L32, so every top-32 element
    // survives and S_tot >= 32 ----
    float mx8 = v[0];
    #pragma unroll
    for (int j = 1; j < 8; ++j) mx8 = fmaxf(mx8, v[j]);
    float srt = mx8;
    sort64_desc_f32(srt, lane);
    float L32 = __int_as_float(__builtin_amdgcn_readlane(__float_as_int(srt), 31));

    // ---- survivor count + exclusive prefix via ballot/mbcnt (no shfl_up chain) ----
    int cnt = 0;
    #pragma unroll
    for (int j = 0; j < 8; ++j) cnt += (v[j] >= L32) ? 1 : 0;
    int sbase = 0, S_tot = 0;
    #pragma unroll
    for (int b = 0; b < 4; ++b) {
        u64 bal = __ballot(((cnt >> b) & 1) != 0);
        int pc = __builtin_amdgcn_mbcnt_hi((u32)(bal >> 32),
                 __builtin_amdgcn_mbcnt_lo((u32)bal, 0));
        sbase += pc << b;
        S_tot += ((int)__popcll(bal)) << b;
    }

    // ---- chunked scatter + sort + merge-prune over 64-slot windows.
    // Chunk 0 is the whole story for ~99.98% of rows (S_tot <= 64).
    // Keys (valbits<<32 | 511-col) unique; desc u64 order == np stable
    // top-k order (value desc, col asc). ----
    int nchunk = (S_tot + 63) >> 6;   // wave-uniform >= 1
    u64 cur = 0ull;
    #pragma unroll 1
    for (int c = 0; c < nchunk; ++c) {
        const int lo = c << 6;
        // scatter survivors whose slot falls in [lo, lo+64)
        int slot = sbase;
        #pragma unroll
        for (int j = 0; j < 8; ++j) {
            bool s = (v[j] >= L32);
            int  rel = slot - lo;
            if (s && rel >= 0 && rel < 64) {
                int col = (j < 4) ? (l4 + j) : (256 + l4 + (j - 4));
                buf[wid][rel] = ((u64)__float_as_uint(v[j]) << 32) | (u32)(511 - col);
            }
            slot += s ? 1 : 0;
        }
        __threadfence_block();
        u64 nxt = (lo + lane < S_tot) ? buf[wid][lane] : 0ull;
        __threadfence_block();   // reads complete before next chunk's writes
        sort64_desc_u64(nxt, lane);
        if (c == 0) {
            cur = nxt;
        } else {
            u64 o = __shfl_xor(nxt, 63);           // nxt[63-lane]
            cur = (cur >= o) ? cur : o;            // top-64 of 128, bitonic
            cas_u64<64,32>(cur, lane);             // descending cleanup
            cas_u64<64,16>(cur, lane);
            cas_u64<64,8>(cur, lane);
            cas_u64<64,4>(cur, lane);
            cas_u64<64,2>(cur, lane);
            cas_u64<64,1>(cur, lane);
        }
    }
    // lane r now holds rank-r key (r < 32 are the selected top-32)

    // ---- coalesced stores: [orig 32 | selected 32] ----
    int src = (lane >= 32) ? (lane - 32) : 0;
    u64 kk = __shfl(cur, src);
    const size_t ob = (size_t)row * Tgt;
    float oid, osc;
    if (lane < Ccand) {
        oid = (float)my_id;
        osc = my_s;
    } else {
        oid = (float)(int)(511 - (u32)(kk & 511ull));
        osc = __uint_as_float((u32)(kk >> 32));
    }
    out_ids[ob + lane]    = oid;
    out_scores[ob + lane] = osc;
}

extern "C" void kernel_launch(void* const* d_in, const int* in_sizes, int n_in,
                              void* d_out, int out_size, void* d_ws, size_t ws_size,
                              hipStream_t stream) {
    const int*   ids    = (const int*)d_in[0];
    const float* scores = (const float*)d_in[1];
    const float* cooc   = (const float*)d_in[2];
    int B = in_sizes[0] / Ccand;
    float* out_ids    = (float*)d_out;
    float* out_scores = out_ids + (size_t)B * Tgt;
    int blocks = (B + 3) / 4;
    hipLaunchKernelGGL(cooc_expand, dim3(blocks), dim3(256), 0, stream,
                       ids, scores, cooc, out_ids, out_scores, B);
}